// Round 7
// baseline (325.815 us; speedup 1.0000x reference)
//
#include <hip/hip_runtime.h>
#include <hip/hip_bf16.h>
#include <stdint.h>

typedef __bf16 bf16x8 __attribute__((ext_vector_type(8)));
typedef float f32x4 __attribute__((ext_vector_type(4)));
typedef int i32x4 __attribute__((ext_vector_type(4)));
typedef unsigned short u16x8 __attribute__((ext_vector_type(8)));
typedef unsigned short u16x4 __attribute__((ext_vector_type(4)));
typedef signed char i8x8 __attribute__((ext_vector_type(8)));
typedef signed char i8x4 __attribute__((ext_vector_type(4)));

__device__ __forceinline__ unsigned short f2bf(float f) {
  union { float f; unsigned int u; } v; v.f = f;
  unsigned int r = v.u + 0x7fffu + ((v.u >> 16) & 1u);   // RNE
  return (unsigned short)(r >> 16);
}

__device__ __forceinline__ f32x4 mfma16(bf16x8 a, bf16x8 b, f32x4 c) {
  return __builtin_amdgcn_mfma_f32_16x16x32_bf16(a, b, c, 0, 0, 0);
}

__device__ __forceinline__ i32x4 mfma_i8(i32x4 a, i32x4 b, i32x4 c) {
  return __builtin_amdgcn_mfma_i32_16x16x64_i8(a, b, c, 0, 0, 0);
}

__device__ __forceinline__ void gload_lds16(const void* g, void* l) {
  __builtin_amdgcn_global_load_lds(
      (const __attribute__((address_space(1))) void*)g,
      (__attribute__((address_space(3))) void*)l, 16, 0, 0);
}

// ---------------- abs-sum reduction (for absmean weight scale) --------------
__global__ void absum_k(const float* __restrict__ w, long n4, float* __restrict__ out) {
  long i = (long)blockIdx.x * blockDim.x + threadIdx.x;
  long stride = (long)gridDim.x * blockDim.x;
  const float4* w4 = (const float4*)w;
  float s = 0.f;
  for (; i < n4; i += stride) {
    float4 v = w4[i];
    s += fabsf(v.x) + fabsf(v.y) + fabsf(v.z) + fabsf(v.w);
  }
  #pragma unroll
  for (int o = 32; o; o >>= 1) s += __shfl_down(s, o);
  __shared__ float sm[4];
  int lane = threadIdx.x & 63, wv = threadIdx.x >> 6;
  if (lane == 0) sm[wv] = s;
  __syncthreads();
  if (threadIdx.x == 0) atomicAdd(out, sm[0] + sm[1] + sm[2] + sm[3]);
}

__global__ void finalize_k(const float* __restrict__ sums, float* __restrict__ sw) {
  int i = threadIdx.x;
  if (i < 4) {
    const float inv[4] = {1.f/(2048.f*2048.f), 1.f/(512.f*2048.f),
                          1.f/(512.f*2048.f), 1.f/(2048.f*2048.f)};
    sw[i] = sums[i] * inv[i] + 1e-5f;
  }
}

// ---------------- ternary weight quantization (store i8 {-1,0,1}) -----------
__global__ void quantw_k(const float* __restrict__ w, signed char* __restrict__ o,
                         long n4, const float* __restrict__ swp) {
  float sw = *swp;
  long i = (long)blockIdx.x * blockDim.x + threadIdx.x;
  long stride = (long)gridDim.x * blockDim.x;
  const float4* w4 = (const float4*)w;
  i8x4* o4 = (i8x4*)o;
  for (; i < n4; i += stride) {
    float4 v = w4[i];
    i8x4 t;
    t[0] = (signed char)(int)fminf(fmaxf(rintf(v.x / sw), -1.f), 1.f);
    t[1] = (signed char)(int)fminf(fmaxf(rintf(v.y / sw), -1.f), 1.f);
    t[2] = (signed char)(int)fminf(fmaxf(rintf(v.z / sw), -1.f), 1.f);
    t[3] = (signed char)(int)fminf(fmaxf(rintf(v.w / sw), -1.f), 1.f);
    o4[i] = t;
  }
}

// ---------------- RoPE tables [2048][64] ------------------------------------
__global__ void ropetab_k(float* __restrict__ cosT, float* __restrict__ sinT) {
  int idx = blockIdx.x * 256 + threadIdx.x;
  int s = idx >> 6, d = idx & 63;
  float freq = expf(-(float)d * (9.210340371976184f / 64.0f));
  float ang = (float)s * freq;
  cosT[idx] = cosf(ang);
  sinT[idx] = sinf(ang);
}

// ---------------- activation quantization (per-row absmax, i8) --------------
__global__ __launch_bounds__(256) void quanta_k(const float* __restrict__ x,
                                                signed char* __restrict__ xq,
                                                float* __restrict__ rs) {
  int row = blockIdx.x;
  const float* xr = x + (size_t)row * 2048;
  int tid = threadIdx.x;
  float4 v0 = ((const float4*)xr)[tid * 2];
  float4 v1 = ((const float4*)xr)[tid * 2 + 1];
  float m = fmaxf(fmaxf(fmaxf(fabsf(v0.x), fabsf(v0.y)), fmaxf(fabsf(v0.z), fabsf(v0.w))),
                  fmaxf(fmaxf(fabsf(v1.x), fabsf(v1.y)), fmaxf(fabsf(v1.z), fabsf(v1.w))));
  #pragma unroll
  for (int o = 32; o; o >>= 1) m = fmaxf(m, __shfl_xor(m, o));
  __shared__ float sm[4];
  if ((tid & 63) == 0) sm[tid >> 6] = m;
  __syncthreads();
  m = fmaxf(fmaxf(sm[0], sm[1]), fmaxf(sm[2], sm[3]));
  float rm = fmaxf(m, 1e-5f);
  float sx = 127.0f / rm;
  float vv[8] = {v0.x, v0.y, v0.z, v0.w, v1.x, v1.y, v1.z, v1.w};
  i8x8 o8;
  #pragma unroll
  for (int j = 0; j < 8; j++) {
    float r = rintf(vv[j] * sx);
    r = fminf(fmaxf(r, -128.f), 127.f);
    o8[j] = (signed char)(int)r;
  }
  ((i8x8*)(xq + (size_t)row * 2048))[tid] = o8;
  if (tid == 0) rs[row] = rm * (1.0f / 127.0f);
}

// ---------------- i8 GEMM (m97 structure, K-step 64, exact int math) --------
__global__ __launch_bounds__(256) void gemm_k(const signed char* __restrict__ A,
                                              const signed char* __restrict__ Bt,
                                              float* __restrict__ C,
                                              int M, int N, int K,
                                              const float* __restrict__ rowscale,
                                              const float* __restrict__ sw, int mode) {
  __shared__ alignas(16) signed char As[128 * 64];
  __shared__ alignas(16) signed char Bs[128 * 64];
  int tid = threadIdx.x;
  int lane = tid & 63, wv = tid >> 6;
  int g = lane >> 4, li = lane & 15;
  int wm = wv >> 1, wn = wv & 1;
  // XCD-aware bijective swizzle (grids are multiples of 8)
  int L = blockIdx.x + gridDim.x * blockIdx.y;
  int nwg = gridDim.x * gridDim.y;
  int swz_id = (L & 7) * (nwg >> 3) + (L >> 3);
  int m0 = (swz_id / gridDim.x) * 128, n0 = (swz_id % gridDim.x) * 128;
  int sr = lane >> 2;                      // staging row 0..15 (64B rows)
  int sc = lane & 3;                       // 16B chunk
  int gc = (sc ^ ((sr >> 1) & 3)) * 16;    // pre-swizzled global chunk (bytes)
  int swz = (g ^ ((li >> 1) & 3)) * 16;    // swizzled read chunk (bytes)
  i32x4 acc[4][4] = {};

  for (int k0 = 0; k0 < K; k0 += 64) {
    __syncthreads();
    #pragma unroll
    for (int j = 0; j < 2; j++) {
      int row = (wv * 2 + j) * 16 + sr;
      gload_lds16(&A[(size_t)(m0 + row) * K + k0 + gc], &As[(wv * 2 + j) * 1024]);
      gload_lds16(&Bt[(size_t)(n0 + row) * K + k0 + gc], &Bs[(wv * 2 + j) * 1024]);
    }
    __syncthreads();
    i32x4 af[4], bfr[4];
    #pragma unroll
    for (int i = 0; i < 4; i++)
      af[i] = *(const i32x4*)&As[(wm * 64 + i * 16 + li) * 64 + swz];
    #pragma unroll
    for (int j = 0; j < 4; j++)
      bfr[j] = *(const i32x4*)&Bs[(wn * 64 + j * 16 + li) * 64 + swz];
    #pragma unroll
    for (int i = 0; i < 4; i++)
      #pragma unroll
      for (int j = 0; j < 4; j++)
        acc[i][j] = mfma_i8(af[i], bfr[j], acc[i][j]);
  }

  #pragma unroll
  for (int i = 0; i < 4; i++) {
    int row = m0 + wm * 64 + i * 16 + g * 4;
    #pragma unroll
    for (int j = 0; j < 4; j++) {
      int col = n0 + wn * 64 + j * 16 + li;
      float s = (mode == 0) ? ((col < 2048) ? sw[0] : (col < 2560 ? sw[1] : sw[2]))
                            : sw[3];
      #pragma unroll
      for (int r = 0; r < 4; r++)
        C[(size_t)(row + r) * N + col] = (float)acc[i][j][r] * (rowscale[row + r] * s);
    }
  }
}

// ---------------- RoPE apply (Q pre-scaled by log2e/sqrt(128)) --------------
__global__ __launch_bounds__(256) void ropeapply_k(const float* __restrict__ raw,
                                                   const float* __restrict__ cosT,
                                                   const float* __restrict__ sinT,
                                                   unsigned short* __restrict__ qb,
                                                   unsigned short* __restrict__ kb) {
  const float CS = 0.1275356234f;  // log2(e)/sqrt(128)
  int r = blockIdx.x;
  int b = r >> 11, s = r & 2047;
  const float* row = raw + (size_t)r * 3072;
  int tid = threadIdx.x;
  for (int idx = tid; idx < 1024; idx += 256) {
    int h = idx >> 6, d = idx & 63;
    float x1 = row[h * 128 + d], x2 = row[h * 128 + d + 64];
    float c = cosT[s * 64 + d], sn = sinT[s * 64 + d];
    size_t base = ((size_t)(b * 16 + h) * 2048 + s) * 128;
    qb[base + d]      = f2bf((x1 * c - x2 * sn) * CS);
    qb[base + d + 64] = f2bf((x2 * c + x1 * sn) * CS);
  }
  {
    int h = tid >> 6, d = tid & 63;
    float x1 = row[2048 + h * 128 + d], x2 = row[2048 + h * 128 + d + 64];
    float c = cosT[s * 64 + d], sn = sinT[s * 64 + d];
    size_t base = ((size_t)(b * 4 + h) * 2048 + s) * 128;
    kb[base + d]      = f2bf(x1 * c - x2 * sn);
    kb[base + d + 64] = f2bf(x2 * c + x1 * sn);
  }
}

// ---------------- V transpose + PV k-permutation ----------------------------
// vtb[b][hk][d][s'] where within each 64-block, position p holds kv
// j(p) = (p>>5)*32 + ((p&7)>>2)*16 + ((p>>3)&3)*4 + (p&3)
__global__ __launch_bounds__(256) void transv_k(const float* __restrict__ raw,
                                                unsigned short* __restrict__ vtb) {
  __shared__ unsigned short T[128][136];
  int sc = blockIdx.x, hk = blockIdx.y, b = blockIdx.z;
  int tid = threadIdx.x;
  #pragma unroll
  for (int i = 0; i < 16; i++) {
    int idx4 = i * 256 + tid;
    int s = idx4 >> 5, d4 = idx4 & 31;
    float4 v = *(const float4*)&raw[((size_t)(b * 2048 + sc * 128 + s)) * 3072 +
                                    2560 + hk * 128 + d4 * 4];
    u16x4 t4;
    t4[0] = f2bf(v.x); t4[1] = f2bf(v.y); t4[2] = f2bf(v.z); t4[3] = f2bf(v.w);
    *(u16x4*)&T[s][d4 * 4] = t4;
  }
  __syncthreads();
  int d = tid >> 1, s0 = (tid & 1) * 64;
  size_t obase = ((size_t)(b * 4 + hk) * 128 + d) * 2048 + sc * 128 + s0;
  #pragma unroll
  for (int j = 0; j < 8; j++) {
    u16x8 o8;
    #pragma unroll
    for (int e = 0; e < 8; e++) {
      int kvp = (j >> 2) * 32 + (e >> 2) * 16 + (j & 3) * 4 + (e & 3);
      o8[e] = T[s0 + kvp][d];
    }
    *(u16x8*)&vtb[obase + j * 8] = o8;
  }
}

// ---------------- causal flash attention (8-wave, deferred-max) -------------
// grid 512 x 512, GLOBAL longest-first: 128 q rows/block (16/wave), KVBLK=64.
// K single-buffer (prefetch between QK and PV), V double-buffer. P in regs.
// T13 deferred-max (THR=8, log2 domain) + lane-partial l accumulation.
__global__ __launch_bounds__(512) void attn_k(const unsigned short* __restrict__ qb,
                                              const unsigned short* __restrict__ kb,
                                              const unsigned short* __restrict__ vtb,
                                              float* __restrict__ out) {
  int gid = blockIdx.x;
  int tq = 15 - (gid >> 5);        // all 32 (h,b) at rank r dispatch together
  int hb = gid & 31;
  int h = hb & 15, b = hb >> 4;
  int wv = threadIdx.x >> 6, lane = threadIdx.x & 63;
  int g = lane >> 4, li = lane & 15;
  int kh = h >> 2;
  const unsigned short* qp = qb + ((size_t)(b * 16 + h) * 2048) * 128;
  const unsigned short* kp = kb + ((size_t)(b * 4 + kh) * 2048) * 128;
  const unsigned short* vp = vtb + ((size_t)(b * 4 + kh) * 128) * 2048;

  __shared__ unsigned short Ks[64 * 128];      // 16KB single buffer
  __shared__ unsigned short Vs[2][128 * 64];   // 32KB double buffer

  int qw = tq * 128 + wv * 16;
  int nt = 2 * tq + 2;
  bf16x8 qf[4];
  #pragma unroll
  for (int kk = 0; kk < 4; kk++)
    qf[kk] = *(const bf16x8*)&qp[(size_t)(qw + li) * 128 + kk * 32 + g * 8];
  f32x4 oacc[8] = {};
  float mrun = -INFINITY, lrun = 0.f;

  // 2 gload_lds per thread per tile per operand (512 threads, 16KB tiles)
  #define STAGE_K(T_) do {                                                  \
    int kv0_ = (T_) * 64;                                                   \
    _Pragma("unroll")                                                       \
    for (int i_ = 0; i_ < 2; i_++) {                                        \
      int r_ = (wv * 2 + i_) * 4 + (lane >> 4);                             \
      int c_ = lane & 15;                                                   \
      gload_lds16(kp + (size_t)(kv0_ + r_) * 128 + ((c_ ^ (r_ & 7)) * 8),   \
                  &Ks[(wv * 2 + i_) * 512]);                                \
    } } while (0)
  #define STAGE_V(T_, BUF_) do {                                            \
    int kv0_ = (T_) * 64;                                                   \
    _Pragma("unroll")                                                       \
    for (int i_ = 0; i_ < 2; i_++) {                                        \
      int d_ = (wv * 2 + i_) * 8 + (lane >> 3);                             \
      int c_ = lane & 7;                                                    \
      gload_lds16(vp + (size_t)d_ * 2048 + kv0_ + ((c_ ^ (d_ & 7)) * 8),    \
                  &Vs[BUF_][(wv * 2 + i_) * 512]);                          \
    } } while (0)

  // prologue
  STAGE_K(0);
  STAGE_V(0, 0);
  if (nt > 1) STAGE_V(1, 1);

  #pragma unroll 1
  for (int t = 0; t < nt; ++t) {
    int kv0 = t * 64;
    // A: wait K[t],V[t] landed (deeper prefetches stay in flight), sync
    if (t == nt - 1) asm volatile("s_waitcnt vmcnt(0)" ::: "memory");
    else             asm volatile("s_waitcnt vmcnt(2)" ::: "memory");
    __builtin_amdgcn_s_barrier();
    asm volatile("" ::: "memory");

    // B: QK^T swapped -> lane holds S[kv=n*16+g*4+r][q=li] (log2 domain)
    f32x4 st[4] = {};
    __builtin_amdgcn_s_setprio(1);
    #pragma unroll
    for (int kk = 0; kk < 4; kk++) {
      #pragma unroll
      for (int n = 0; n < 4; n++) {
        bf16x8 kf = *(const bf16x8*)&Ks[(n * 16 + li) * 128 +
                                        (((kk * 4 + g) ^ (li & 7)) * 8)];
        st[n] = mfma16(kf, qf[kk], st[n]);
      }
    }
    __builtin_amdgcn_s_setprio(0);

    // C: all waves done reading Ks -> prefetch K[t+1] into it
    asm volatile("" ::: "memory");
    __builtin_amdgcn_s_barrier();
    asm volatile("" ::: "memory");
    if (t + 1 < nt) STAGE_K(t + 1);

    // D: softmax, deferred-max (THR=8 in log2 domain)
    if (kv0 + 63 > qw) {     // causal mask (block spans 128 q rows)
      int qrel = qw + li - kv0;
      #pragma unroll
      for (int n = 0; n < 4; n++)
        #pragma unroll
        for (int r = 0; r < 4; r++)
          if ((n * 16 + g * 4 + r) > qrel) st[n][r] = -INFINITY;
    }
    float mx = fmaxf(fmaxf(fmaxf(st[0][0], st[0][1]), fmaxf(st[0][2], st[0][3])),
                     fmaxf(fmaxf(st[1][0], st[1][1]), fmaxf(st[1][2], st[1][3])));
    mx = fmaxf(mx, fmaxf(fmaxf(fmaxf(st[2][0], st[2][1]), fmaxf(st[2][2], st[2][3])),
                         fmaxf(fmaxf(st[3][0], st[3][1]), fmaxf(st[3][2], st[3][3]))));
    if (!__all(mx - mrun <= 8.0f)) {
      float rmx = fmaxf(mx, __shfl_xor(mx, 16));
      rmx = fmaxf(rmx, __shfl_xor(rmx, 32));
      float mnew = fmaxf(mrun, rmx);
      float alpha = exp2f(mrun - mnew);
      lrun *= alpha;                      // lane-partial l rescale (own row)
      float ar[4];
      #pragma unroll
      for (int r = 0; r < 4; r++) ar[r] = __shfl(alpha, g * 4 + r, 64);
      #pragma unroll
      for (int dn = 0; dn < 8; dn++)
        #pragma unroll
        for (int r = 0; r < 4; r++) oacc[dn][r] *= ar[r];
      mrun = mnew;
    }
    float lsum = 0.f;
    bf16x8 pa0, pa1;
    #pragma unroll
    for (int n = 0; n < 4; n++) {
      #pragma unroll
      for (int r = 0; r < 4; r++) {
        float p = exp2f(st[n][r] - mrun);
        lsum += p;
        if (n < 2) pa0[(n & 1) * 4 + r] = (__bf16)p;
        else       pa1[(n & 1) * 4 + r] = (__bf16)p;
      }
    }
    lrun += lsum;                         // lane-partial; reduced after loop

    // E: PV from Vs[t&1] (pre-permuted so pa0/pa1 feed directly)
    int cur = t & 1;
    __builtin_amdgcn_s_setprio(1);
    #pragma unroll
    for (int dn = 0; dn < 8; dn++) {
      int d = dn * 16 + li;
      bf16x8 vf0 = *(const bf16x8*)&Vs[cur][d * 64 + ((g ^ (li & 7)) * 8)];
      bf16x8 vf1 = *(const bf16x8*)&Vs[cur][d * 64 + (((4 + g) ^ (li & 7)) * 8)];
      oacc[dn] = mfma16(pa0, vf0, oacc[dn]);
      oacc[dn] = mfma16(pa1, vf1, oacc[dn]);
    }
    __builtin_amdgcn_s_setprio(0);

    // F: all waves done reading Vs[cur] -> prefetch V[t+2] into it
    asm volatile("" ::: "memory");
    __builtin_amdgcn_s_barrier();
    asm volatile("" ::: "memory");
    if (t + 2 < nt) STAGE_V(t + 2, cur);
  }
  #undef STAGE_K
  #undef STAGE_V

  // reduce lane-partial l across the 4 k-slot lanes of each row
  lrun += __shfl_xor(lrun, 16);
  lrun += __shfl_xor(lrun, 32);
  float linv = 1.0f / lrun;
  float lr_[4];
  #pragma unroll
  for (int r = 0; r < 4; r++) lr_[r] = __shfl(linv, g * 4 + r, 64);
  size_t obase = ((size_t)(b * 2048 + qw + g * 4)) * 2048 + h * 128;
  #pragma unroll
  for (int dn = 0; dn < 8; dn++)
    #pragma unroll
    for (int r = 0; r < 4; r++)
      out[obase + (size_t)r * 2048 + dn * 16 + li] = oacc[dn][r] * lr_[r];
}

// ---------------------------------------------------------------------------
extern "C" void kernel_launch(void* const* d_in, const int* in_sizes, int n_in,
                              void* d_out, int out_size, void* d_ws, size_t ws_size,
                              hipStream_t stream) {
  const float* x  = (const float*)d_in[0];
  const float* Wq = (const float*)d_in[1];
  const float* Wk = (const float*)d_in[2];
  const float* Wv = (const float*)d_in[3];
  const float* Wo = (const float*)d_in[4];
  float* out = (float*)d_out;

  char* ws = (char*)d_ws;
  size_t off = 0;
  auto alloc = [&](size_t bytes) -> void* {
    void* p = ws + off;
    off = (off + bytes + 255) & ~(size_t)255;
    return p;
  };
  float* sums = (float*)alloc(16);
  float* sw   = (float*)alloc(16);
  float* rs   = (float*)alloc(4096 * 4);
  float* rs2  = (float*)alloc(4096 * 4);
  float* cosT = (float*)alloc((size_t)131072 * 4);
  float* sinT = (float*)alloc((size_t)131072 * 4);
  signed char* Wcat = (signed char*)alloc((size_t)3072 * 2048);
  signed char* Wot  = (signed char*)alloc((size_t)2048 * 2048);
  unsigned short* qb   = (unsigned short*)alloc((size_t)2 * 16 * 2048 * 128 * 2);
  unsigned short* kb   = (unsigned short*)alloc((size_t)2 * 4 * 2048 * 128 * 2);
  unsigned short* vtb  = (unsigned short*)alloc((size_t)2 * 4 * 128 * 2048 * 2);
  signed char* xq   = (signed char*)alloc((size_t)4096 * 2048);
  float* raw  = (float*)alloc((size_t)4096 * 3072 * 4);
  float* attn = raw;   // reuse: raw dead after ropeapply/transv

  hipMemsetAsync(sums, 0, 16, stream);
  absum_k<<<256, 256, 0, stream>>>(Wq, (long)2048 * 2048 / 4, sums + 0);
  absum_k<<<128, 256, 0, stream>>>(Wk, (long)512 * 2048 / 4, sums + 1);
  absum_k<<<128, 256, 0, stream>>>(Wv, (long)512 * 2048 / 4, sums + 2);
  absum_k<<<256, 256, 0, stream>>>(Wo, (long)2048 * 2048 / 4, sums + 3);
  finalize_k<<<1, 4, 0, stream>>>(sums, sw);
  quantw_k<<<512, 256, 0, stream>>>(Wq, Wcat, (long)2048 * 2048 / 4, sw + 0);
  quantw_k<<<128, 256, 0, stream>>>(Wk, Wcat + (size_t)2048 * 2048, (long)512 * 2048 / 4, sw + 1);
  quantw_k<<<128, 256, 0, stream>>>(Wv, Wcat + (size_t)2560 * 2048, (long)512 * 2048 / 4, sw + 2);
  quantw_k<<<512, 256, 0, stream>>>(Wo, Wot, (long)2048 * 2048 / 4, sw + 3);
  ropetab_k<<<512, 256, 0, stream>>>(cosT, sinT);
  quanta_k<<<4096, 256, 0, stream>>>(x, xq, rs);
  dim3 g1(3072 / 128, 4096 / 128);
  gemm_k<<<g1, 256, 0, stream>>>(xq, Wcat, raw, 4096, 3072, 2048, rs, sw, 0);
  ropeapply_k<<<4096, 256, 0, stream>>>(raw, cosT, sinT, qb, kb);
  transv_k<<<dim3(16, 4, 2), 256, 0, stream>>>(raw, vtb);
  attn_k<<<512, 512, 0, stream>>>(qb, kb, vtb, attn);
  quanta_k<<<4096, 256, 0, stream>>>(attn, xq, rs2);
  dim3 g2(2048 / 128, 4096 / 128);
  gemm_k<<<g2, 256, 0, stream>>>(xq, Wot, out, 4096, 2048, 2048, rs2, sw, 1);
}